// Round 2
// baseline (162.477 us; speedup 1.0000x reference)
//
#include <hip/hip_runtime.h>

typedef __bf16 bf16;
typedef __bf16 bf16x8 __attribute__((ext_vector_type(8)));
typedef float f32x4 __attribute__((ext_vector_type(4)));
typedef unsigned short u16;
typedef u16 u16x8 __attribute__((ext_vector_type(8)));
typedef unsigned int u32;

#define BATCH 64
#define NODES 512
#define AMINO 64
#define NTYPES 20
#define RMAX 13
#define NJT 26           // 26 j-tiles of 16
#define PADA 72          // padded amino stride in LDS planes (elements)
#define TPAD 100         // tbuf row stride in dwords (mult of 4 -> 16B aligned reads)
#define REP 4            // diagnostic in-kernel repeat (idempotent) -- makes main visible in rocprof top-5

__constant__ int c_res_lens[NTYPES] = {4,10,7,7,5,8,8,3,9,7,7,8,7,10,6,5,6,13,11,6};

// fp32 -> bf16, exact round-to-nearest-even, pure bit ops
__device__ __forceinline__ u16 f2bf(float f) {
    u32 u; __builtin_memcpy(&u, &f, 4);
    u32 r = u + 0x7FFFu + ((u >> 16) & 1u);
    return (u16)(r >> 16);
}

// int64 vs int32 probe for type_ids: odd words all-zero <=> int64 high halves.
__device__ __forceinline__ int detect_i64(const int* __restrict__ p) {
    int z = 0;
#pragma unroll
    for (int k = 0; k < 16; ++k) z |= p[2 * k + 1];
    return z == 0;
}
__device__ __forceinline__ int tid_at(const int* __restrict__ p, int n, int is64) {
    return p[is64 ? 2 * n : n];
}

// ---------------- prep kernel ----------------
// blocks 0..259: swizzle fp32 W into B-fragment-linear bf16 layout:
//   chunk = (t*NJT + jt)*2 + kh ; lane l holds W[t][a=kh*32+(l>>4)*8+i][j=jt*16+(l&15)]
// block 260: exclusive prefix sum of residue lengths -> S[0..511]
__global__ __launch_bounds__(256) void prep_kernel(const float* __restrict__ W,
                                                   const int* __restrict__ type_ids,
                                                   u16* __restrict__ wswz,
                                                   int* __restrict__ S) {
    if (blockIdx.x < 260) {
        int g = blockIdx.x * 256 + threadIdx.x;     // over 20*26*2*64 = 66560 lanes
        if (g >= NTYPES * NJT * 2 * 64) return;
        int lane = g & 63;
        int chunk = g >> 6;
        int kh = chunk & 1;
        int tj = chunk >> 1;
        int t = tj / NJT;
        int jt = tj - t * NJT;
        int q = lane >> 4, c = lane & 15;
        int a0 = kh * 32 + q * 8;
        int j = jt * 16 + c;
        u16x8 v;
#pragma unroll
        for (int i = 0; i < 8; ++i)
            v[i] = f2bf(W[(size_t)(t * AMINO + a0 + i) * (RMAX * 32) + j]);
        *(u16x8*)(wswz + (size_t)chunk * 512 + lane * 8) = v;
    } else {
        __shared__ int s[256];
        int is64 = detect_i64(type_ids);
        int i = threadIdx.x;
        int la = c_res_lens[tid_at(type_ids, 2 * i, is64)];
        int lb = c_res_lens[tid_at(type_ids, 2 * i + 1, is64)];
        s[i] = la + lb;
        __syncthreads();
        for (int off = 1; off < 256; off <<= 1) {
            int v = (i >= off) ? s[i - off] : 0;
            __syncthreads();
            s[i] += v;
            __syncthreads();
        }
        int excl = s[i] - (la + lb);     // exclusive over pairs
        S[2 * i] = excl;
        S[2 * i + 1] = excl + la;
    }
}

// ---------------- main kernel ----------------
// block = (node n, m-tile m): 16 batches. 4 waves; wave w handles r = w, w+4, ...
// Stores go through a per-wave LDS transpose tile -> fully coalesced dwordx4.
__global__ __launch_bounds__(256) void main_kernel(const float* __restrict__ x,
                                                   const int* __restrict__ type_ids,
                                                   const int* __restrict__ S,
                                                   const u16* __restrict__ wswz,
                                                   float* __restrict__ out,
                                                   int G) {
    // union: staging planes (6912 B) then per-wave transpose tiles (25600 B)
    __shared__ __align__(16) char smem[4 * 16 * TPAD * 4];
    u16 (*planes)[16][PADA] = (u16 (*)[16][PADA])smem;     // [v][b16][a]
    float (*tbuf)[16][TPAD] = (float (*)[16][TPAD])smem;   // [wave][row][col]

    const int bid = blockIdx.x;
    const int n = bid >> 2;
    const int m = bid & 3;
    const int tid = threadIdx.x;
    const int w = tid >> 6;
    const int l = tid & 63;

    const int is64 = detect_i64(type_ids);
    const int t = tid_at(type_ids, n, is64);
    const int len = c_res_lens[t];
    const int s0 = S[n];

    // ---- stage x[m*16..m*16+15, n, :, :] into bf16 v-planes ----
#pragma unroll
    for (int i = 0; i < 4; ++i) {
        int b16 = i * 4 + w;
        const float* src = x + ((size_t)(m * 16 + b16) * NODES + n) * 192 + l * 3;
        float v0 = src[0];
        float v1 = src[1];
        float v2 = src[2];
        planes[0][b16][l] = f2bf(v0);
        planes[1][b16][l] = f2bf(v1);
        planes[2][b16][l] = f2bf(v2);
    }
    __syncthreads();

    const int q = l >> 4;
    const int c = l & 15;

    // ---- preload A fragments: lane holds A[row=c][k=kh*32+q*8+i] ----
    union Frag { u16x8 u; bf16x8 b; };
    Frag Af[3][2];
#pragma unroll
    for (int v = 0; v < 3; ++v)
#pragma unroll
        for (int kh = 0; kh < 2; ++kh)
            Af[v][kh].u = *(const u16x8*)(&planes[v][c][kh * 32 + q * 8]);

    __syncthreads();   // planes dead -> tbuf may reuse the region

    // ---- precompute coalesced store geometry (r-invariant) ----
    // flat = s*256 + l*4 over [0,1536): row = flat/96 (batch sub-row), idx = flat%96
    int ldsoff[6];
    const float* outbase[6];
#pragma unroll
    for (int s = 0; s < 6; ++s) {
        int flat = s * 256 + l * 4;
        int row = flat / 96;
        int idx = flat - row * 96;
        ldsoff[s] = row * TPAD + idx;
        outbase[s] = out + (size_t)(m * 16 + row) * G * 96 + idx;
    }
    float* twave = &tbuf[w][0][0];

    for (int rep = 0; rep < REP; ++rep) {
        asm volatile("" ::: "memory");   // keep reps from collapsing (diagnostic)
        for (int r = w; r < len; r += 4) {
            Frag Bf[2][2];
#pragma unroll
            for (int jj = 0; jj < 2; ++jj)
#pragma unroll
                for (int kh = 0; kh < 2; ++kh)
                    Bf[jj][kh].u = *(const u16x8*)(wswz +
                                    (size_t)((t * NJT + (2 * r + jj)) * 2 + kh) * 512 + l * 8);

            const int g = s0 + r;   // output row index within G

            f32x4 acc[2][3];
            const f32x4 z = {0.f, 0.f, 0.f, 0.f};
#pragma unroll
            for (int jj = 0; jj < 2; ++jj)
#pragma unroll
                for (int v = 0; v < 3; ++v) {
                    f32x4 a0 = __builtin_amdgcn_mfma_f32_16x16x32_bf16(Af[v][0].b, Bf[jj][0].b, z, 0, 0, 0);
                    acc[jj][v] = __builtin_amdgcn_mfma_f32_16x16x32_bf16(Af[v][1].b, Bf[jj][1].b, a0, 0, 0, 0);
                }

            // ---- transpose via per-wave LDS tile ----
#pragma unroll
            for (int jj = 0; jj < 2; ++jj)
#pragma unroll
                for (int reg = 0; reg < 4; ++reg) {
                    float* p = &tbuf[w][q * 4 + reg][(jj * 16 + c) * 3];
                    p[0] = acc[jj][0][reg];
                    p[1] = acc[jj][1][reg];
                    p[2] = acc[jj][2][reg];
                }

            // ---- coalesced dwordx4 stores: 6 per lane, 384 B contiguous per row-chunk ----
#pragma unroll
            for (int s = 0; s < 6; ++s) {
                f32x4 vv = *(const f32x4*)(twave + ldsoff[s]);
                *(f32x4*)((float*)outbase[s] + (size_t)g * 96) = vv;
            }
        }
    }
}

extern "C" void kernel_launch(void* const* d_in, const int* in_sizes, int n_in,
                              void* d_out, int out_size, void* d_ws, size_t ws_size,
                              hipStream_t stream) {
    const float* x = (const float*)d_in[0];    // fp32 (B, N, 64, 3)
    const float* W = (const float*)d_in[1];    // fp32 (20, 64, 416)
    const int* type_ids = (const int*)d_in[2]; // int32 or int64 (autodetected), 512
    int G = out_size / (BATCH * 32 * 3);       // valid (node,residue) rows

    int* S = (int*)d_ws;                                   // 512 ints
    u16* wswz = (u16*)((char*)d_ws + 4096);                // 20*26*2*512 bf16 ≈ 1.06 MB

    prep_kernel<<<261, 256, 0, stream>>>(W, type_ids, wswz, S);
    main_kernel<<<NODES * 4, 256, 0, stream>>>(x, type_ids, S, wswz, (float*)d_out, G);
}

// Round 3
// 129.441 us; speedup vs baseline: 1.2552x; 1.2552x over previous
//
#include <hip/hip_runtime.h>

typedef __bf16 bf16;
typedef __bf16 bf16x8 __attribute__((ext_vector_type(8)));
typedef float f32x4 __attribute__((ext_vector_type(4)));
typedef unsigned short u16;
typedef u16 u16x8 __attribute__((ext_vector_type(8)));
typedef unsigned int u32;

#define BATCH 64
#define NODES 512
#define AMINO 64
#define NTYPES 20
#define RMAX 13
#define NJT 26           // 26 j-tiles of 16
#define PADA 72          // padded amino stride in LDS planes (elements)
#define TPAD 100         // tbuf row stride in dwords (mult of 4 -> 16B aligned reads)

__constant__ int c_res_lens[NTYPES] = {4,10,7,7,5,8,8,3,9,7,7,8,7,10,6,5,6,13,11,6};

// fp32 -> bf16, exact round-to-nearest-even, pure bit ops
__device__ __forceinline__ u16 f2bf(float f) {
    u32 u; __builtin_memcpy(&u, &f, 4);
    u32 r = u + 0x7FFFu + ((u >> 16) & 1u);
    return (u16)(r >> 16);
}

// int64 vs int32 probe for type_ids: odd words all-zero <=> int64 high halves.
__device__ __forceinline__ int detect_i64(const int* __restrict__ p) {
    int z = 0;
#pragma unroll
    for (int k = 0; k < 16; ++k) z |= p[2 * k + 1];
    return z == 0;
}
__device__ __forceinline__ int tid_at(const int* __restrict__ p, int n, int is64) {
    return p[is64 ? 2 * n : n];
}

// ---------------- prep kernel ----------------
// blocks 0..259: swizzle fp32 W into B-fragment-linear bf16 layout:
//   chunk = (t*NJT + jt)*2 + kh ; lane l holds W[t][a=kh*32+(l>>4)*8+i][j=jt*16+(l&15)]
// block 260: exclusive prefix sum of residue lengths -> S[0..511]
__global__ __launch_bounds__(256) void prep_kernel(const float* __restrict__ W,
                                                   const int* __restrict__ type_ids,
                                                   u16* __restrict__ wswz,
                                                   int* __restrict__ S) {
    if (blockIdx.x < 260) {
        int g = blockIdx.x * 256 + threadIdx.x;     // over 20*26*2*64 = 66560 lanes
        if (g >= NTYPES * NJT * 2 * 64) return;
        int lane = g & 63;
        int chunk = g >> 6;
        int kh = chunk & 1;
        int tj = chunk >> 1;
        int t = tj / NJT;
        int jt = tj - t * NJT;
        int q = lane >> 4, c = lane & 15;
        int a0 = kh * 32 + q * 8;
        int j = jt * 16 + c;
        u16x8 v;
#pragma unroll
        for (int i = 0; i < 8; ++i)
            v[i] = f2bf(W[(size_t)(t * AMINO + a0 + i) * (RMAX * 32) + j]);
        *(u16x8*)(wswz + (size_t)chunk * 512 + lane * 8) = v;
    } else {
        __shared__ int s[256];
        int is64 = detect_i64(type_ids);
        int i = threadIdx.x;
        int la = c_res_lens[tid_at(type_ids, 2 * i, is64)];
        int lb = c_res_lens[tid_at(type_ids, 2 * i + 1, is64)];
        s[i] = la + lb;
        __syncthreads();
        for (int off = 1; off < 256; off <<= 1) {
            int v = (i >= off) ? s[i - off] : 0;
            __syncthreads();
            s[i] += v;
            __syncthreads();
        }
        int excl = s[i] - (la + lb);     // exclusive over pairs
        S[2 * i] = excl;
        S[2 * i + 1] = excl + la;
    }
}

// ---------------- main kernel ----------------
// block = (node n, m-tile m): 16 batches. 4 waves; wave w handles r = w, w+4, ...
// Stores go through a per-wave LDS transpose tile -> fully coalesced nontemporal dwordx4.
__global__ __launch_bounds__(256) void main_kernel(const float* __restrict__ x,
                                                   const int* __restrict__ type_ids,
                                                   const int* __restrict__ S,
                                                   const u16* __restrict__ wswz,
                                                   float* __restrict__ out,
                                                   int G) {
    __shared__ __align__(16) u16 planes[3][16][PADA];     // staging: 6912 B
    __shared__ __align__(16) float tbuf[4][16][TPAD];     // per-wave transpose: 25600 B

    const int bid = blockIdx.x;
    const int n = bid >> 2;
    const int m = bid & 3;
    const int tid = threadIdx.x;
    const int w = tid >> 6;
    const int l = tid & 63;

    const int is64 = detect_i64(type_ids);
    const int t = tid_at(type_ids, n, is64);
    const int len = c_res_lens[t];
    const int s0 = S[n];

    // ---- stage x[m*16..m*16+15, n, :, :] into bf16 v-planes ----
#pragma unroll
    for (int i = 0; i < 4; ++i) {
        int b16 = i * 4 + w;
        const float* src = x + ((size_t)(m * 16 + b16) * NODES + n) * 192 + l * 3;
        float v0 = src[0];
        float v1 = src[1];
        float v2 = src[2];
        planes[0][b16][l] = f2bf(v0);
        planes[1][b16][l] = f2bf(v1);
        planes[2][b16][l] = f2bf(v2);
    }
    __syncthreads();

    const int q = l >> 4;
    const int c = l & 15;

    // ---- preload A fragments: lane holds A[row=c][k=kh*32+q*8+i] ----
    union Frag { u16x8 u; bf16x8 b; };
    Frag Af[3][2];
#pragma unroll
    for (int v = 0; v < 3; ++v)
#pragma unroll
        for (int kh = 0; kh < 2; ++kh)
            Af[v][kh].u = *(const u16x8*)(&planes[v][c][kh * 32 + q * 8]);

    // ---- precompute coalesced store geometry (r-invariant) ----
    // flat = s*256 + l*4 over [0,1536): row = flat/96 (batch sub-row), idx = flat%96
    int ldsoff[6];
    const float* outbase[6];
#pragma unroll
    for (int s = 0; s < 6; ++s) {
        int flat = s * 256 + l * 4;
        int row = flat / 96;
        int idx = flat - row * 96;
        ldsoff[s] = row * TPAD + idx;
        outbase[s] = out + (size_t)(m * 16 + row) * G * 96 + idx;
    }
    float* twave = &tbuf[w][0][0];

    for (int r = w; r < len; r += 4) {
        Frag Bf[2][2];
#pragma unroll
        for (int jj = 0; jj < 2; ++jj)
#pragma unroll
            for (int kh = 0; kh < 2; ++kh)
                Bf[jj][kh].u = *(const u16x8*)(wswz +
                                (size_t)((t * NJT + (2 * r + jj)) * 2 + kh) * 512 + l * 8);

        const int g = s0 + r;   // output row index within G

        f32x4 acc[2][3];
        const f32x4 z = {0.f, 0.f, 0.f, 0.f};
#pragma unroll
        for (int jj = 0; jj < 2; ++jj)
#pragma unroll
            for (int v = 0; v < 3; ++v) {
                f32x4 a0 = __builtin_amdgcn_mfma_f32_16x16x32_bf16(Af[v][0].b, Bf[jj][0].b, z, 0, 0, 0);
                acc[jj][v] = __builtin_amdgcn_mfma_f32_16x16x32_bf16(Af[v][1].b, Bf[jj][1].b, a0, 0, 0, 0);
            }

        // ---- transpose via per-wave LDS tile (same-wave: no barrier needed) ----
#pragma unroll
        for (int jj = 0; jj < 2; ++jj)
#pragma unroll
            for (int reg = 0; reg < 4; ++reg) {
                float* p = &tbuf[w][q * 4 + reg][(jj * 16 + c) * 3];
                p[0] = acc[jj][0][reg];
                p[1] = acc[jj][1][reg];
                p[2] = acc[jj][2][reg];
            }

        // ---- coalesced nontemporal dwordx4 stores: 6/lane, 384 B contiguous/row ----
#pragma unroll
        for (int s = 0; s < 6; ++s) {
            f32x4 vv = *(const f32x4*)(twave + ldsoff[s]);
            __builtin_nontemporal_store(vv, (f32x4*)((float*)outbase[s] + (size_t)g * 96));
        }
    }
}

extern "C" void kernel_launch(void* const* d_in, const int* in_sizes, int n_in,
                              void* d_out, int out_size, void* d_ws, size_t ws_size,
                              hipStream_t stream) {
    const float* x = (const float*)d_in[0];    // fp32 (B, N, 64, 3)
    const float* W = (const float*)d_in[1];    // fp32 (20, 64, 416)
    const int* type_ids = (const int*)d_in[2]; // int32 or int64 (autodetected), 512
    int G = out_size / (BATCH * 32 * 3);       // valid (node,residue) rows

    int* S = (int*)d_ws;                                   // 512 ints
    u16* wswz = (u16*)((char*)d_ws + 4096);                // 20*26*2*512 bf16 ≈ 1.06 MB

    prep_kernel<<<261, 256, 0, stream>>>(W, type_ids, wswz, S);
    main_kernel<<<NODES * 4, 256, 0, stream>>>(x, type_ids, S, wswz, (float*)d_out, G);
}

// Round 4
// 127.085 us; speedup vs baseline: 1.2785x; 1.0185x over previous
//
#include <hip/hip_runtime.h>

typedef __bf16 bf16;
typedef __bf16 bf16x8 __attribute__((ext_vector_type(8)));
typedef float f32x4 __attribute__((ext_vector_type(4)));
typedef unsigned short u16;
typedef u16 u16x8 __attribute__((ext_vector_type(8)));
typedef unsigned int u32;

#define BATCH 64
#define NODES 512
#define AMINO 64
#define NTYPES 20
#define RMAX 13
#define NJT 26           // 26 j-tiles of 16
#define PADA 72          // padded amino stride in LDS planes (elements)
#define TPAD 100         // tbuf row stride in dwords (mult of 4 -> 16B aligned reads)

__constant__ int c_res_lens[NTYPES] = {4,10,7,7,5,8,8,3,9,7,7,8,7,10,6,5,6,13,11,6};

// fp32 -> bf16, exact round-to-nearest-even, pure bit ops
__device__ __forceinline__ u16 f2bf(float f) {
    u32 u; __builtin_memcpy(&u, &f, 4);
    u32 r = u + 0x7FFFu + ((u >> 16) & 1u);
    return (u16)(r >> 16);
}

// int64 vs int32 probe for type_ids: odd words all-zero <=> int64 high halves.
__device__ __forceinline__ int detect_i64(const int* __restrict__ p) {
    int z = 0;
#pragma unroll
    for (int k = 0; k < 16; ++k) z |= p[2 * k + 1];
    return z == 0;
}
__device__ __forceinline__ int tid_at(const int* __restrict__ p, int n, int is64) {
    return p[is64 ? 2 * n : n];
}

// ---------------- prep kernel ----------------
// blocks 0..259: swizzle fp32 W into B-fragment-linear bf16 layout:
//   chunk = (t*NJT + jt)*2 + kh ; lane l holds W[t][a=kh*32+(l>>4)*8+i][j=jt*16+(l&15)]
// block 260: exclusive prefix sum of residue lengths -> S[0..511]
__global__ __launch_bounds__(256) void prep_kernel(const float* __restrict__ W,
                                                   const int* __restrict__ type_ids,
                                                   u16* __restrict__ wswz,
                                                   int* __restrict__ S) {
    if (blockIdx.x < 260) {
        int g = blockIdx.x * 256 + threadIdx.x;     // over 20*26*2*64 = 66560 lanes
        if (g >= NTYPES * NJT * 2 * 64) return;
        int lane = g & 63;
        int chunk = g >> 6;
        int kh = chunk & 1;
        int tj = chunk >> 1;
        int t = tj / NJT;
        int jt = tj - t * NJT;
        int q = lane >> 4, c = lane & 15;
        int a0 = kh * 32 + q * 8;
        int j = jt * 16 + c;
        u16x8 v;
#pragma unroll
        for (int i = 0; i < 8; ++i)
            v[i] = f2bf(W[(size_t)(t * AMINO + a0 + i) * (RMAX * 32) + j]);
        *(u16x8*)(wswz + (size_t)chunk * 512 + lane * 8) = v;
    } else {
        __shared__ int s[256];
        int is64 = detect_i64(type_ids);
        int i = threadIdx.x;
        int la = c_res_lens[tid_at(type_ids, 2 * i, is64)];
        int lb = c_res_lens[tid_at(type_ids, 2 * i + 1, is64)];
        s[i] = la + lb;
        __syncthreads();
        for (int off = 1; off < 256; off <<= 1) {
            int v = (i >= off) ? s[i - off] : 0;
            __syncthreads();
            s[i] += v;
            __syncthreads();
        }
        int excl = s[i] - (la + lb);     // exclusive over pairs
        S[2 * i] = excl;
        S[2 * i + 1] = excl + la;
    }
}

// ---------------- main kernel ----------------
// block = (node n, m-tile m): 16 batches. 4 waves; wave w handles r = w, w+4, ...
// Stores go through a per-wave LDS transpose tile -> fully coalesced dwordx4.
// LDS: planes unioned with tbuf (25.6 KB total) -> 6 blocks/CU (matches the
// round-2 config that measured 17.4 us per steady-state rep).
__global__ __launch_bounds__(256) void main_kernel(const float* __restrict__ x,
                                                   const int* __restrict__ type_ids,
                                                   const int* __restrict__ S,
                                                   const u16* __restrict__ wswz,
                                                   float* __restrict__ out,
                                                   int G) {
    // union: staging planes (6912 B) then per-wave transpose tiles (25600 B)
    __shared__ __align__(16) char smem[4 * 16 * TPAD * 4];
    u16 (*planes)[16][PADA] = (u16 (*)[16][PADA])smem;     // [v][b16][a]
    float (*tbuf)[16][TPAD] = (float (*)[16][TPAD])smem;   // [wave][row][col]

    const int bid = blockIdx.x;
    const int n = bid >> 2;
    const int m = bid & 3;
    const int tid = threadIdx.x;
    const int w = tid >> 6;
    const int l = tid & 63;

    const int is64 = detect_i64(type_ids);
    const int t = tid_at(type_ids, n, is64);
    const int len = c_res_lens[t];
    const int s0 = S[n];

    // ---- stage x[m*16..m*16+15, n, :, :] into bf16 v-planes ----
#pragma unroll
    for (int i = 0; i < 4; ++i) {
        int b16 = i * 4 + w;
        const float* src = x + ((size_t)(m * 16 + b16) * NODES + n) * 192 + l * 3;
        float v0 = src[0];
        float v1 = src[1];
        float v2 = src[2];
        planes[0][b16][l] = f2bf(v0);
        planes[1][b16][l] = f2bf(v1);
        planes[2][b16][l] = f2bf(v2);
    }
    __syncthreads();

    const int q = l >> 4;
    const int c = l & 15;

    // ---- preload A fragments: lane holds A[row=c][k=kh*32+q*8+i] ----
    union Frag { u16x8 u; bf16x8 b; };
    Frag Af[3][2];
#pragma unroll
    for (int v = 0; v < 3; ++v)
#pragma unroll
        for (int kh = 0; kh < 2; ++kh)
            Af[v][kh].u = *(const u16x8*)(&planes[v][c][kh * 32 + q * 8]);

    __syncthreads();   // planes dead -> tbuf may reuse the region

    // ---- precompute coalesced store geometry (r-invariant) ----
    // flat = s*256 + l*4 over [0,1536): row = flat/96 (batch sub-row), idx = flat%96
    int ldsoff[6];
    const float* outbase[6];
#pragma unroll
    for (int s = 0; s < 6; ++s) {
        int flat = s * 256 + l * 4;
        int row = flat / 96;
        int idx = flat - row * 96;
        ldsoff[s] = row * TPAD + idx;
        outbase[s] = out + (size_t)(m * 16 + row) * G * 96 + idx;
    }
    float* twave = &tbuf[w][0][0];

    for (int r = w; r < len; r += 4) {
        Frag Bf[2][2];
#pragma unroll
        for (int jj = 0; jj < 2; ++jj)
#pragma unroll
            for (int kh = 0; kh < 2; ++kh)
                Bf[jj][kh].u = *(const u16x8*)(wswz +
                                (size_t)((t * NJT + (2 * r + jj)) * 2 + kh) * 512 + l * 8);

        const int g = s0 + r;   // output row index within G

        f32x4 acc[2][3];
        const f32x4 z = {0.f, 0.f, 0.f, 0.f};
#pragma unroll
        for (int jj = 0; jj < 2; ++jj)
#pragma unroll
            for (int v = 0; v < 3; ++v) {
                f32x4 a0 = __builtin_amdgcn_mfma_f32_16x16x32_bf16(Af[v][0].b, Bf[jj][0].b, z, 0, 0, 0);
                acc[jj][v] = __builtin_amdgcn_mfma_f32_16x16x32_bf16(Af[v][1].b, Bf[jj][1].b, a0, 0, 0, 0);
            }

        // ---- transpose via per-wave LDS tile (same-wave: no barrier needed) ----
#pragma unroll
        for (int jj = 0; jj < 2; ++jj)
#pragma unroll
            for (int reg = 0; reg < 4; ++reg) {
                float* p = &tbuf[w][q * 4 + reg][(jj * 16 + c) * 3];
                p[0] = acc[jj][0][reg];
                p[1] = acc[jj][1][reg];
                p[2] = acc[jj][2][reg];
            }

        // ---- coalesced dwordx4 stores: 6 per lane, 384 B contiguous per row-chunk ----
#pragma unroll
        for (int s = 0; s < 6; ++s) {
            f32x4 vv = *(const f32x4*)(twave + ldsoff[s]);
            *(f32x4*)((float*)outbase[s] + (size_t)g * 96) = vv;
        }
    }
}

extern "C" void kernel_launch(void* const* d_in, const int* in_sizes, int n_in,
                              void* d_out, int out_size, void* d_ws, size_t ws_size,
                              hipStream_t stream) {
    const float* x = (const float*)d_in[0];    // fp32 (B, N, 64, 3)
    const float* W = (const float*)d_in[1];    // fp32 (20, 64, 416)
    const int* type_ids = (const int*)d_in[2]; // int32 or int64 (autodetected), 512
    int G = out_size / (BATCH * 32 * 3);       // valid (node,residue) rows

    int* S = (int*)d_ws;                                   // 512 ints
    u16* wswz = (u16*)((char*)d_ws + 4096);                // 20*26*2*512 bf16 ≈ 1.06 MB

    prep_kernel<<<261, 256, 0, stream>>>(W, type_ids, wswz, S);
    main_kernel<<<NODES * 4, 256, 0, stream>>>(x, type_ids, S, wswz, (float*)d_out, G);
}